// Round 2
// baseline (1894640.625 us; speedup 1.0000x reference)
//
#include <hip/hip_runtime.h>
#include <cstdint>

#define TT 512

typedef unsigned short u16;
typedef uint32_t u32;
typedef float  floatx4 __attribute__((ext_vector_type(4)));
typedef short  short8  __attribute__((ext_vector_type(8)));
typedef u32    u32x4   __attribute__((ext_vector_type(4)));

__device__ __forceinline__ float bf2f(u16 u) {
    union { u32 i; float f; } v; v.i = ((u32)u) << 16; return v.f;
}
__device__ __forceinline__ u16 f2bf(float f) {
    union { float f; u32 i; } v; v.f = f;
    u32 x = v.i;
    return (u16)((x + 0x7fffu + ((x >> 16) & 1u)) >> 16);  // RNE
}
__device__ __forceinline__ float sigm(float x)  { return 1.0f / (1.0f + __expf(-x)); }
__device__ __forceinline__ float tanh_(float x) { return 2.0f / (1.0f + __expf(-2.0f * x)) - 1.0f; }
#define BF(p) (*(const short8*)(p))

// ---- coherent access helpers.
// SAFE (FASTP=false): sc0 sc1 -> coherent at the device MALL (works across XCDs).
// FAST (FASTP=true):  sc0 only -> coherent at the XCD's shared L2. Valid ONLY when
// all 8 partner blocks of a group share one XCD (verified at runtime via XCC_ID
// handshake). L2-hit latency ~100ns vs MALL ~700ns per trip; weights stay warm.
template<bool FASTP> __device__ __forceinline__ void stg32(u32* p, u32 v) {
    if constexpr (FASTP)
        asm volatile("global_store_dword %0, %1, off sc0" :: "v"(p), "v"(v) : "memory");
    else
        asm volatile("global_store_dword %0, %1, off sc0 sc1" :: "v"(p), "v"(v) : "memory");
}
template<bool FASTP> __device__ __forceinline__ void stgf(float* p, float v) {
    if constexpr (FASTP)
        asm volatile("global_store_dword %0, %1, off sc0" :: "v"(p), "v"(v) : "memory");
    else
        asm volatile("global_store_dword %0, %1, off sc0 sc1" :: "v"(p), "v"(v) : "memory");
}
template<bool FASTP> __device__ __forceinline__ u32 ldg32p(const u32* p) {   // self-waiting poll
    u32 v;
    if constexpr (FASTP)
        asm volatile("global_load_dword %0, %1, off sc0\n\ts_waitcnt vmcnt(0)"
                     : "=v"(v) : "v"(p) : "memory");
    else
        asm volatile("global_load_dword %0, %1, off sc0 sc1\n\ts_waitcnt vmcnt(0)"
                     : "=v"(v) : "v"(p) : "memory");
    return v;
}
template<bool FASTP> __device__ __forceinline__ u32x4 ldg128(const u32x4* p) {  // pipelined
    u32x4 v;
    if constexpr (FASTP)
        asm volatile("global_load_dwordx4 %0, %1, off sc0" : "=v"(v) : "v"(p));
    else
        asm volatile("global_load_dwordx4 %0, %1, off sc0 sc1" : "=v"(v) : "v"(p));
    return v;
}
template<bool FASTP> __device__ __forceinline__ float ldgf(const float* p) {    // pipelined
    float v;
    if constexpr (FASTP)
        asm volatile("global_load_dword %0, %1, off sc0" : "=v"(v) : "v"(p));
    else
        asm volatile("global_load_dword %0, %1, off sc0 sc1" : "=v"(v) : "v"(p));
    return v;
}
// always-MALL helpers (handshake only; must work cross-XCD under any placement)
__device__ __forceinline__ void st_coh32(u32* p, u32 v) {
    asm volatile("global_store_dword %0, %1, off sc0 sc1" :: "v"(p), "v"(v) : "memory");
}
__device__ __forceinline__ u32 ld_coh32(const u32* p) {
    u32 v;
    asm volatile("global_load_dword %0, %1, off sc0 sc1\n\ts_waitcnt vmcnt(0)"
                 : "=v"(v) : "v"(p) : "memory");
    return v;
}
__device__ __forceinline__ void vmcnt0() { asm volatile("s_waitcnt vmcnt(0)" ::: "memory"); }
#define KEEP(x) asm volatile("" : "+v"(x))   // consume-after-wait fence (rule #18)

__global__ void zero_flags(u32* flg) { st_coh32(&flg[threadIdx.x], 0u); }   // 256 words: flg + xcc_tab

#define MFMA_(A_, B_, ACC) ACC = __builtin_amdgcn_mfma_f32_16x16x32_bf16(A_, B_, ACC, 0, 0, 0)
#define MS1(ACC, GATE_) { short8 A_ = BF(fs0 + (GATE_) * 4096); \
    MFMA_(A_, Bh, ACC); MFMA_(A_, Bl, ACC); }
#define MS3(ACC, GATE_) { short8 A1_ = BF(fs1 + (GATE_) * 4096); \
    MFMA_(A1_, Bh, ACC); MFMA_(A1_, Bl, ACC); \
    short8 A2_ = BF(fs2 + (GATE_) * 4096); \
    MFMA_(A2_, Ch, ACC); MFMA_(A2_, Cl, ACC); }

// layer-0 gate: update c0, publish packed h0(p+1) via coherent write-through store
#define GATE0(R) { \
    const int d_ = dg16 + 4 * q + (R); \
    float zi_ = Zi[R] + b0s[0][d_], zf_ = Zf[R] + b0s[1][d_]; \
    float zg_ = Zg[R] + b0s[2][d_], zo_ = Zo[R] + b0s[3][d_]; \
    float c_  = sigm(zf_) * c0v[R] + sigm(zi_) * tanh_(zg_); c0v[R] = c_; \
    float hv_ = sigm(zo_) * tanh_(c_); \
    u16 hi_ = f2bf(hv_); u16 lo_ = f2bf(hv_ - bf2f(hi_)); \
    stg32<FASTP>(&hx0w[d_ * 16 + bq], ((u32)hi_ << 16) | (u32)lo_); }
#define GATE1L(R) { \
    const int d_ = dg16 + 4 * q + (R); \
    float zi_ = Yi[R] + b1s[0][d_], zf_ = Yf[R] + b1s[1][d_]; \
    float zg_ = Yg[R] + b1s[2][d_], zo_ = Yo[R] + b1s[3][d_]; \
    float c_  = sigm(zf_) * c1v[R] + sigm(zi_) * tanh_(zg_); c1v[R] = c_; \
    float hv_ = sigm(zo_) * tanh_(c_); \
    u16 hi_ = f2bf(hv_); u16 lo_ = f2bf(hv_ - bf2f(hi_)); \
    stg32<FASTP>(&hx1w[d_ * 16 + bq], ((u32)hi_ << 16) | (u32)lo_); \
    part += hv_ * who_s[d_]; }

#define UNPACK0(v, i4) { const int d_ = (i4) >> 2, bb_ = ((i4) & 3) * 4; \
    h0hi[bb_ + 0][d_] = (short)((v)[0] >> 16); h0lo[bb_ + 0][d_] = (short)((v)[0] & 0xFFFFu); \
    h0hi[bb_ + 1][d_] = (short)((v)[1] >> 16); h0lo[bb_ + 1][d_] = (short)((v)[1] & 0xFFFFu); \
    h0hi[bb_ + 2][d_] = (short)((v)[2] >> 16); h0lo[bb_ + 2][d_] = (short)((v)[2] & 0xFFFFu); \
    h0hi[bb_ + 3][d_] = (short)((v)[3] >> 16); h0lo[bb_ + 3][d_] = (short)((v)[3] & 0xFFFFu); }
#define UNPACK1(v, i4) { const int d_ = (i4) >> 2, bb_ = ((i4) & 3) * 4; \
    h1hi[bb_ + 0][d_] = (short)((v)[0] >> 16); h1lo[bb_ + 0][d_] = (short)((v)[0] & 0xFFFFu); \
    h1hi[bb_ + 1][d_] = (short)((v)[1] >> 16); h1lo[bb_ + 1][d_] = (short)((v)[1] & 0xFFFFu); \
    h1hi[bb_ + 2][d_] = (short)((v)[2] >> 16); h1lo[bb_ + 2][d_] = (short)((v)[2] & 0xFFFFu); \
    h1hi[bb_ + 3][d_] = (short)((v)[3] >> 16); h1lo[bb_ + 3][d_] = (short)((v)[3] & 0xFFFFu); }

// The 512-phase skewed pipeline, templated on coherence scope.
template<bool FASTP>
__device__ __forceinline__ void phase_loop(
    short (*h0hi)[264], short (*h0lo)[264], short (*h1hi)[264], short (*h1lo)[264],
    float (*b0s)[256], float (*b1s)[256], float* who_s, float (*osc)[16],
    const short* fb0, const short* fb1, const short* fb2,
    u32* hx0, u32* hx1, float* posc, u32* flg, float* out,
    int tid, int w, int lane, int bq, int q, int g, int j, int bglo, float bho)
{
    const int dg16 = (2 * j + (w & 1)) * 16;
    u32* myflag = flg + g * 8 + j;
    float c0v[4] = {0.f, 0.f, 0.f, 0.f}, c1v[4] = {0.f, 0.f, 0.f, 0.f};

    for (int p = 0; p <= TT; ++p) {
        const int pb = p & 1;
        u32* hx0w = hx0 + pb * 65536 + g * 4096;
        u32* hx1w = hx1 + pb * 65536 + g * 4096;

        if (w < 2 && p < TT) {          // layer 0
            floatx4 Zi = {0.f,0.f,0.f,0.f}, Zf = {0.f,0.f,0.f,0.f};
            floatx4 Zg = {0.f,0.f,0.f,0.f}, Zo = {0.f,0.f,0.f,0.f};
#pragma unroll 1
            for (int s = 0; s < 8; ++s) {
                const int hoff = s * 32 + q * 8;
                short8 Bh = BF(&h0hi[bq][hoff]);
                short8 Bl = BF(&h0lo[bq][hoff]);
                const short* fs0 = fb0 + s * 512;
                MS1(Zi, 0) MS1(Zf, 1) MS1(Zg, 2) MS1(Zo, 3)
            }
            GATE0(0) GATE0(1) GATE0(2) GATE0(3)
        }
        if (w >= 2 && p >= 1) {         // layer 1
            floatx4 Yi = {0.f,0.f,0.f,0.f}, Yf = {0.f,0.f,0.f,0.f};
            floatx4 Yg = {0.f,0.f,0.f,0.f}, Yo = {0.f,0.f,0.f,0.f};
#pragma unroll 1
            for (int s = 0; s < 8; ++s) {
                const int hoff = s * 32 + q * 8;
                short8 Bh = BF(&h0hi[bq][hoff]);
                short8 Bl = BF(&h0lo[bq][hoff]);
                short8 Ch = BF(&h1hi[bq][hoff]);
                short8 Cl = BF(&h1lo[bq][hoff]);
                const short* fs1 = fb1 + s * 512;
                const short* fs2 = fb2 + s * 512;
                MS3(Yi, 0) MS3(Yf, 1) MS3(Yg, 2) MS3(Yo, 3)
            }
            float part = 0.0f;
            GATE1L(0) GATE1L(1) GATE1L(2) GATE1L(3)
            part += __shfl_xor(part, 16, 64);
            part += __shfl_xor(part, 32, 64);
            if (q == 0) osc[w - 2][bq] = part;
        }
        vmcnt0();                        // every wave: its hx stores acked at coherence point
        __syncthreads();                 // osc visible in LDS; all waves drained
        if (p >= 1 && tid < 16)
            stgf<FASTP>(posc + pb * 2048 + g * 128 + j * 16 + tid, osc[0][tid] + osc[1][tid]);
        if (tid == 0) {                  // wave-level waitcnt drains lanes 0..15 posc stores
            vmcnt0();
            stg32<FASTP>(myflag, (u32)(p + 1));
        }
        if (tid < 8) {                   // spin on coherent loads
            const u32 tgt = (u32)(p + 1);
            int it = 0;
            while (ldg32p<FASTP>(flg + g * 8 + tid) < tgt) {
                __builtin_amdgcn_s_sleep(1);
                if (++it > 50000) break; // finite-wrong, never hang
            }
        }
        __syncthreads();
        // ---- pipelined coherent readback: h0(p+1), h1(p)
        u32x4 va0, va1, va2, va3, vb0, vb1, vb2, vb3;
        float po0, po1, po2, po3, po4, po5, po6, po7;
        const u32x4* s4a = (const u32x4*)hx0w;
        const u32x4* s4b = (const u32x4*)hx1w;
        const bool doout = (p >= 1) && (j == 0) && (tid < 16);
        if (p < TT) {
            va0 = ldg128<FASTP>(s4a + tid);
            va1 = ldg128<FASTP>(s4a + tid + 256);
            va2 = ldg128<FASTP>(s4a + tid + 512);
            va3 = ldg128<FASTP>(s4a + tid + 768);
        }
        if (p >= 1) {
            vb0 = ldg128<FASTP>(s4b + tid);
            vb1 = ldg128<FASTP>(s4b + tid + 256);
            vb2 = ldg128<FASTP>(s4b + tid + 512);
            vb3 = ldg128<FASTP>(s4b + tid + 768);
        }
        if (doout) {
            const float* pp = posc + pb * 2048 + g * 128 + tid;
            po0 = ldgf<FASTP>(pp);       po1 = ldgf<FASTP>(pp + 16);
            po2 = ldgf<FASTP>(pp + 32);  po3 = ldgf<FASTP>(pp + 48);
            po4 = ldgf<FASTP>(pp + 64);  po5 = ldgf<FASTP>(pp + 80);
            po6 = ldgf<FASTP>(pp + 96);  po7 = ldgf<FASTP>(pp + 112);
        }
        vmcnt0();                        // all readback loads complete
        if (p < TT) {
            KEEP(va0); KEEP(va1); KEEP(va2); KEEP(va3);
            UNPACK0(va0, tid); UNPACK0(va1, tid + 256);
            UNPACK0(va2, tid + 512); UNPACK0(va3, tid + 768);
        }
        if (p >= 1) {
            KEEP(vb0); KEEP(vb1); KEEP(vb2); KEEP(vb3);
            UNPACK1(vb0, tid); UNPACK1(vb1, tid + 256);
            UNPACK1(vb2, tid + 512); UNPACK1(vb3, tid + 768);
        }
        if (doout) {                     // assemble out[t = p-1]
            KEEP(po0); KEEP(po1); KEEP(po2); KEEP(po3);
            KEEP(po4); KEEP(po5); KEEP(po6); KEEP(po7);
            float o = bho + ((po0 + po1) + (po2 + po3)) + ((po4 + po5) + (po6 + po7));
            out[(bglo + tid) * TT + (p - 1)] = o;
        }
        __syncthreads();                 // LDS h planes ready for next phase
    }
}

// 128 blocks = 16 groups x 8 dim-slices. Mapping g=bid&15, j=bid>>4 puts all 8
// slices of a group at the same bid%8 -> same XCD under round-robin dispatch.
// Runtime XCC_ID handshake verifies this; fast path (L2-scope sc0) engages only
// when confirmed, else the MALL-scope sc0sc1 path (round-1 behavior) runs.
__launch_bounds__(256, 2)
__global__ void lstm_skew(const float* __restrict__ latent, const float* __restrict__ W_lh,
                          const float* __restrict__ b_lh,
                          const float* __restrict__ W_hh0,
                          const float* __restrict__ b_ih0, const float* __restrict__ b_hh0,
                          const float* __restrict__ W_ih1, const float* __restrict__ W_hh1,
                          const float* __restrict__ b_ih1, const float* __restrict__ b_hh1,
                          const float* __restrict__ W_ho,  const float* __restrict__ b_ho,
                          short* __restrict__ frag, u32* __restrict__ hx0, u32* __restrict__ hx1,
                          float* __restrict__ posc, u32* __restrict__ flg,
                          float* __restrict__ out)
{
    __shared__ __align__(16) short h0hi[16][264], h0lo[16][264];   // h0(p), full 256 dims
    __shared__ __align__(16) short h1hi[16][264], h1lo[16][264];   // h1(p-1)
    __shared__ float b0s[4][256], b1s[4][256];
    __shared__ float who_s[256];
    __shared__ float osc[2][16];
    __shared__ int fast_s;

    const int tid  = threadIdx.x;      // 256 threads, 4 waves
    const int w    = tid >> 6;
    const int lane = tid & 63;
    const int bq   = lane & 15;
    const int q    = lane >> 4;
    const int bid  = blockIdx.x;
    const int g    = bid & 15;         // batch group
    const int j    = bid >> 4;         // dim slice 0..7
    const int bglo = g * 16;
    u32* xcct = flg + 128;             // xcc handshake table (zeroed by zero_flags)

    // ---- stage this slice's weight fragments (identical bytes across groups: benign race)
    for (int i = tid; i < 12288; i += 256) {
        const int l8 = i & 63, s8 = (i >> 6) & 7, gate8 = (i >> 9) & 3;
        const int dgl = (i >> 11) & 1, G = i >> 12;
        const int dgw = 2 * j + dgl;
        const float* W = (G == 0) ? W_hh0 : (G == 1) ? W_ih1 : W_hh1;
        const float* src = W + (gate8 * 256 + dgw * 16 + (l8 & 15)) * 256
                             + s8 * 32 + (l8 >> 4) * 8;
        short8 v;
#pragma unroll
        for (int jj = 0; jj < 8; ++jj) v[jj] = (short)f2bf(src[jj]);
        *(short8*)(frag + (size_t)(l8 * 8 + s8 * 512 + gate8 * 4096 + dgw * 16384 + G * 262144)) = v;
    }
    for (int i = tid; i < 1024; i += 256) {
        b0s[i >> 8][i & 255] = b_ih0[i] + b_hh0[i];
        b1s[i >> 8][i & 255] = b_ih1[i] + b_hh1[i];
    }
    if (tid < 256) who_s[tid] = W_ho[tid];

    // h_init = latent @ W_lh.T + b_lh (fp32), split hi/lo
    {
        const int b = tid >> 4, d0 = (tid & 15) * 16;
        const float* lr = latent + (bglo + b) * 128;
#pragma unroll
        for (int jj = 0; jj < 16; ++jj) {
            const int d = d0 + jj;
            const float* wr = W_lh + d * 128;
            float acc = b_lh[d];
            for (int c = 0; c < 128; c += 4) {
                float4 lv = *(const float4*)(lr + c);
                float4 wv = *(const float4*)(wr + c);
                acc += lv.x * wv.x + lv.y * wv.y + lv.z * wv.z + lv.w * wv.w;
            }
            u16 hi = f2bf(acc), lo = f2bf(acc - bf2f(hi));
            h0hi[b][d] = (short)hi; h0lo[b][d] = (short)lo;
            h1hi[b][d] = (short)hi; h1lo[b][d] = (short)lo;
        }
    }

    // ---- XCC placement handshake (device-scope, one-time)
    u32 myxcc;
    asm volatile("s_getreg_b32 %0, hwreg(HW_REG_XCC_ID)" : "=s"(myxcc));
    myxcc &= 0xFFu;
    if (tid == 0) {
        vmcnt0();
        st_coh32(xcct + bid, myxcc | 0x100u);
    }
    u32 part_ok = 0;
    if (tid < 8) {
        const u32* pp = xcct + g + 16 * tid;     // partner block (g, jj=tid)
        u32 v = 0; int it = 0;
        do {
            v = ld_coh32(pp);
            if (++it > 200000) break;
        } while (!(v & 0x100u));
        part_ok = ((v & 0x100u) && ((v & 0xFFu) == myxcc)) ? 1u : 0u;
    }
    unsigned long long bal = __ballot(part_ok != 0);
    if (tid == 0) fast_s = ((bal & 0xFFull) == 0xFFull) ? 1 : 0;
    __syncthreads();                     // fast_s + LDS h planes ready

    const int dgw   = 2 * j + (w & 1);
    const short* fb0 = frag + dgw * 16384 + (size_t)lane * 8;
    const short* fb1 = frag + 262144 + dgw * 16384 + (size_t)lane * 8;
    const short* fb2 = fb1 + 262144;
    const float bho = b_ho[0];

    if (fast_s)
        phase_loop<true>(h0hi, h0lo, h1hi, h1lo, b0s, b1s, who_s, osc,
                         fb0, fb1, fb2, hx0, hx1, posc, flg, out,
                         tid, w, lane, bq, q, g, j, bglo, bho);
    else
        phase_loop<false>(h0hi, h0lo, h1hi, h1lo, b0s, b1s, who_s, osc,
                          fb0, fb1, fb2, hx0, hx1, posc, flg, out,
                          tid, w, lane, bq, q, g, j, bglo, bho);
}

extern "C" void kernel_launch(void* const* d_in, const int* in_sizes, int n_in,
                              void* d_out, int out_size, void* d_ws, size_t ws_size,
                              hipStream_t stream)
{
    const float* latent = (const float*)d_in[0];
    const float* W_lh   = (const float*)d_in[1];
    const float* b_lh   = (const float*)d_in[2];
    // d_in[3] = W_ih0: unused (layer-0 inputs are all-zero)
    const float* W_hh0  = (const float*)d_in[4];
    const float* b_ih0  = (const float*)d_in[5];
    const float* b_hh0  = (const float*)d_in[6];
    const float* W_ih1  = (const float*)d_in[7];
    const float* W_hh1  = (const float*)d_in[8];
    const float* b_ih1  = (const float*)d_in[9];
    const float* b_hh1  = (const float*)d_in[10];
    const float* W_ho   = (const float*)d_in[11];
    const float* b_ho   = (const float*)d_in[12];

    char* ws = (char*)d_ws;
    short* frag = (short*)ws;                     // 1,572,864 B
    u32*   hx0  = (u32*)(ws + 1572864);           //   524,288 B (2 parities)
    u32*   hx1  = (u32*)(ws + 2097152);           //   524,288 B
    float* posc = (float*)(ws + 2621440);         //    16,384 B (2 parities)
    u32*   flg  = (u32*)(ws + 2637824);           //     1,024 B: flags[128] + xcc_tab[128]

    zero_flags<<<dim3(1), dim3(256), 0, stream>>>(flg);
    lstm_skew<<<dim3(128), dim3(256), 0, stream>>>(latent, W_lh, b_lh,
                                                   W_hh0, b_ih0, b_hh0,
                                                   W_ih1, W_hh1, b_ih1, b_hh1,
                                                   W_ho, b_ho,
                                                   frag, hx0, hx1, posc, flg,
                                                   (float*)d_out);
}

// Round 3
// 3378.342 us; speedup vs baseline: 560.8196x; 560.8196x over previous
//
#include <hip/hip_runtime.h>
#include <cstdint>

#define TT 512

typedef unsigned short u16;
typedef uint32_t u32;
typedef float  floatx4 __attribute__((ext_vector_type(4)));
typedef short  short8  __attribute__((ext_vector_type(8)));
typedef u32    u32x4   __attribute__((ext_vector_type(4)));

__device__ __forceinline__ float bf2f(u16 u) {
    union { u32 i; float f; } v; v.i = ((u32)u) << 16; return v.f;
}
__device__ __forceinline__ u16 f2bf(float f) {
    union { float f; u32 i; } v; v.f = f;
    u32 x = v.i;
    return (u16)((x + 0x7fffu + ((x >> 16) & 1u)) >> 16);  // RNE
}
__device__ __forceinline__ float sigm(float x)  { return 1.0f / (1.0f + __expf(-x)); }
__device__ __forceinline__ float tanh_(float x) { return 2.0f / (1.0f + __expf(-2.0f * x)) - 1.0f; }
#define BF(p) (*(const short8*)(p))

// ---- DEVICE-scope (agent) coherent accesses: sc1 only.
// gfx950 SC encoding: sc0sc1 = system scope (round 1: worked, but forced every
// exchange store through to DRAM -> 361 MB WRITE_SIZE and ~900cy trips).
// sc1 = device scope: coherent at the MALL across XCDs, but MALL-allocating.
// sc0-only (round 2) is NOT sufficient for cross-CU polling (stale L1 -> spin
// timeout every phase, 1.89 s). Ordering remains manual: per-wave
// s_waitcnt vmcnt(0) acks stores at the coherence point before the flag.
__device__ __forceinline__ void st32_dev(u32* p, u32 v) {
    asm volatile("global_store_dword %0, %1, off sc1" :: "v"(p), "v"(v) : "memory");
}
__device__ __forceinline__ void stf_dev(float* p, float v) {
    asm volatile("global_store_dword %0, %1, off sc1" :: "v"(p), "v"(v) : "memory");
}
__device__ __forceinline__ u32 ld32_poll(const u32* p) {           // self-waiting (spin)
    u32 v;
    asm volatile("global_load_dword %0, %1, off sc1\n\ts_waitcnt vmcnt(0)"
                 : "=v"(v) : "v"(p) : "memory");
    return v;
}
__device__ __forceinline__ u32x4 ld128_dev(const u32x4* p) {       // pipelined: no wait
    u32x4 v;
    asm volatile("global_load_dwordx4 %0, %1, off sc1" : "=v"(v) : "v"(p));
    return v;
}
__device__ __forceinline__ float ldf_dev(const float* p) {         // pipelined: no wait
    float v;
    asm volatile("global_load_dword %0, %1, off sc1" : "=v"(v) : "v"(p));
    return v;
}
__device__ __forceinline__ void vmcnt0() { asm volatile("s_waitcnt vmcnt(0)" ::: "memory"); }
#define KEEP(x) asm volatile("" : "+v"(x))   // consume-after-wait fence (rule #18)

__global__ void zero_flags(u32* flg) {       // system scope: strictly stronger, one-time
    asm volatile("global_store_dword %0, %1, off sc0 sc1" :: "v"(&flg[threadIdx.x]), "v"(0u) : "memory");
}

#define MFMA_(A_, B_, ACC) ACC = __builtin_amdgcn_mfma_f32_16x16x32_bf16(A_, B_, ACC, 0, 0, 0)
#define MS1(ACC, GATE_) { short8 A_ = BF(fs0 + (GATE_) * 4096); \
    MFMA_(A_, Bh, ACC); MFMA_(A_, Bl, ACC); }
#define MS3(ACC, GATE_) { short8 A1_ = BF(fs1 + (GATE_) * 4096); \
    MFMA_(A1_, Bh, ACC); MFMA_(A1_, Bl, ACC); \
    short8 A2_ = BF(fs2 + (GATE_) * 4096); \
    MFMA_(A2_, Ch, ACC); MFMA_(A2_, Cl, ACC); }

// layer-0 gate: update c0, publish packed h0(p+1) via device-scope store
#define GATE0(R) { \
    const int d_ = dg16 + 4 * q + (R); \
    float zi_ = Zi[R] + b0s[0][d_], zf_ = Zf[R] + b0s[1][d_]; \
    float zg_ = Zg[R] + b0s[2][d_], zo_ = Zo[R] + b0s[3][d_]; \
    float c_  = sigm(zf_) * c0v[R] + sigm(zi_) * tanh_(zg_); c0v[R] = c_; \
    float hv_ = sigm(zo_) * tanh_(c_); \
    u16 hi_ = f2bf(hv_); u16 lo_ = f2bf(hv_ - bf2f(hi_)); \
    st32_dev(&hx0w[d_ * 16 + bq], ((u32)hi_ << 16) | (u32)lo_); }
#define GATE1L(R) { \
    const int d_ = dg16 + 4 * q + (R); \
    float zi_ = Yi[R] + b1s[0][d_], zf_ = Yf[R] + b1s[1][d_]; \
    float zg_ = Yg[R] + b1s[2][d_], zo_ = Yo[R] + b1s[3][d_]; \
    float c_  = sigm(zf_) * c1v[R] + sigm(zi_) * tanh_(zg_); c1v[R] = c_; \
    float hv_ = sigm(zo_) * tanh_(c_); \
    u16 hi_ = f2bf(hv_); u16 lo_ = f2bf(hv_ - bf2f(hi_)); \
    st32_dev(&hx1w[d_ * 16 + bq], ((u32)hi_ << 16) | (u32)lo_); \
    part += hv_ * who_s[d_]; }

#define UNPACK0(v, i4) { const int d_ = (i4) >> 2, bb_ = ((i4) & 3) * 4; \
    h0hi[bb_ + 0][d_] = (short)((v)[0] >> 16); h0lo[bb_ + 0][d_] = (short)((v)[0] & 0xFFFFu); \
    h0hi[bb_ + 1][d_] = (short)((v)[1] >> 16); h0lo[bb_ + 1][d_] = (short)((v)[1] & 0xFFFFu); \
    h0hi[bb_ + 2][d_] = (short)((v)[2] >> 16); h0lo[bb_ + 2][d_] = (short)((v)[2] & 0xFFFFu); \
    h0hi[bb_ + 3][d_] = (short)((v)[3] >> 16); h0lo[bb_ + 3][d_] = (short)((v)[3] & 0xFFFFu); }
#define UNPACK1(v, i4) { const int d_ = (i4) >> 2, bb_ = ((i4) & 3) * 4; \
    h1hi[bb_ + 0][d_] = (short)((v)[0] >> 16); h1lo[bb_ + 0][d_] = (short)((v)[0] & 0xFFFFu); \
    h1hi[bb_ + 1][d_] = (short)((v)[1] >> 16); h1lo[bb_ + 1][d_] = (short)((v)[1] & 0xFFFFu); \
    h1hi[bb_ + 2][d_] = (short)((v)[2] >> 16); h1lo[bb_ + 2][d_] = (short)((v)[2] & 0xFFFFu); \
    h1hi[bb_ + 3][d_] = (short)((v)[3] >> 16); h1lo[bb_ + 3][d_] = (short)((v)[3] & 0xFFFFu); }

// 128 blocks = 16 groups x 8 dim-slices. Skewed pipeline, 3 barriers/phase:
//   compute (hx + posc device-scope stores inline) -> per-wave vmcnt(0) -> bar
//   -> tid0 flag store (all waves' data already acked) -> tid<8 spin -> bar
//   -> pipelined device-scope readback -> vmcnt(0) -> unpack -> bar.
__launch_bounds__(256, 2)
__global__ void lstm_skew(const float* __restrict__ latent, const float* __restrict__ W_lh,
                          const float* __restrict__ b_lh,
                          const float* __restrict__ W_hh0,
                          const float* __restrict__ b_ih0, const float* __restrict__ b_hh0,
                          const float* __restrict__ W_ih1, const float* __restrict__ W_hh1,
                          const float* __restrict__ b_ih1, const float* __restrict__ b_hh1,
                          const float* __restrict__ W_ho,  const float* __restrict__ b_ho,
                          short* __restrict__ frag, u32* __restrict__ hx0, u32* __restrict__ hx1,
                          float* __restrict__ posc, u32* __restrict__ flg,
                          float* __restrict__ out)
{
    __shared__ __align__(16) short h0hi[16][264], h0lo[16][264];   // h0(p), full 256 dims
    __shared__ __align__(16) short h1hi[16][264], h1lo[16][264];   // h1(p-1)
    __shared__ float b0s[4][256], b1s[4][256];
    __shared__ float who_s[256];

    const int tid  = threadIdx.x;      // 256 threads, 4 waves
    const int w    = tid >> 6;
    const int lane = tid & 63;
    const int bq   = lane & 15;
    const int q    = lane >> 4;
    const int g    = blockIdx.x & 15;  // batch group
    const int j    = blockIdx.x >> 4;  // dim slice 0..7
    const int bglo = g * 16;

    // ---- stage this slice's weight fragments (identical bytes across groups: benign race)
    for (int i = tid; i < 12288; i += 256) {
        const int l8 = i & 63, s8 = (i >> 6) & 7, gate8 = (i >> 9) & 3;
        const int dgl = (i >> 11) & 1, G = i >> 12;
        const int dgw = 2 * j + dgl;
        const float* W = (G == 0) ? W_hh0 : (G == 1) ? W_ih1 : W_hh1;
        const float* src = W + (gate8 * 256 + dgw * 16 + (l8 & 15)) * 256
                             + s8 * 32 + (l8 >> 4) * 8;
        short8 v;
#pragma unroll
        for (int jj = 0; jj < 8; ++jj) v[jj] = (short)f2bf(src[jj]);
        *(short8*)(frag + (size_t)(l8 * 8 + s8 * 512 + gate8 * 4096 + dgw * 16384 + G * 262144)) = v;
    }
    for (int i = tid; i < 1024; i += 256) {
        b0s[i >> 8][i & 255] = b_ih0[i] + b_hh0[i];
        b1s[i >> 8][i & 255] = b_ih1[i] + b_hh1[i];
    }
    if (tid < 256) who_s[tid] = W_ho[tid];

    // h_init = latent @ W_lh.T + b_lh (fp32), split hi/lo
    {
        const int b = tid >> 4, d0 = (tid & 15) * 16;
        const float* lr = latent + (bglo + b) * 128;
#pragma unroll
        for (int jj = 0; jj < 16; ++jj) {
            const int d = d0 + jj;
            const float* wr = W_lh + d * 128;
            float acc = b_lh[d];
            for (int c = 0; c < 128; c += 4) {
                float4 lv = *(const float4*)(lr + c);
                float4 wv = *(const float4*)(wr + c);
                acc += lv.x * wv.x + lv.y * wv.y + lv.z * wv.z + lv.w * wv.w;
            }
            u16 hi = f2bf(acc), lo = f2bf(acc - bf2f(hi));
            h0hi[b][d] = (short)hi; h0lo[b][d] = (short)lo;
            h1hi[b][d] = (short)hi; h1lo[b][d] = (short)lo;
        }
    }
    __syncthreads();

    // wave roles: w0,w1 = layer 0 (dim-groups 2j, 2j+1); w2,w3 = layer 1
    const int dgw   = 2 * j + (w & 1);
    const int dg16  = dgw * 16;
    const short* fb0 = frag + dgw * 16384 + (size_t)lane * 8;
    const short* fb1 = frag + 262144 + dgw * 16384 + (size_t)lane * 8;
    const short* fb2 = fb1 + 262144;
    u32* myflag = flg + g * 8 + j;
    float c0v[4] = {0.f, 0.f, 0.f, 0.f}, c1v[4] = {0.f, 0.f, 0.f, 0.f};
    const float bho = b_ho[0];

    for (int p = 0; p <= TT; ++p) {
        const int pb = p & 1;
        u32* hx0w = hx0 + pb * 65536 + g * 4096;
        u32* hx1w = hx1 + pb * 65536 + g * 4096;
        float* poscw = posc + pb * 4096 + g * 256;   // [j][half][16]

        if (w < 2 && p < TT) {          // layer 0
            floatx4 Zi = {0.f,0.f,0.f,0.f}, Zf = {0.f,0.f,0.f,0.f};
            floatx4 Zg = {0.f,0.f,0.f,0.f}, Zo = {0.f,0.f,0.f,0.f};
#pragma unroll 1
            for (int s = 0; s < 8; ++s) {
                const int hoff = s * 32 + q * 8;
                short8 Bh = BF(&h0hi[bq][hoff]);
                short8 Bl = BF(&h0lo[bq][hoff]);
                const short* fs0 = fb0 + s * 512;
                MS1(Zi, 0) MS1(Zf, 1) MS1(Zg, 2) MS1(Zo, 3)
            }
            GATE0(0) GATE0(1) GATE0(2) GATE0(3)
        }
        if (w >= 2 && p >= 1) {         // layer 1
            floatx4 Yi = {0.f,0.f,0.f,0.f}, Yf = {0.f,0.f,0.f,0.f};
            floatx4 Yg = {0.f,0.f,0.f,0.f}, Yo = {0.f,0.f,0.f,0.f};
#pragma unroll 1
            for (int s = 0; s < 8; ++s) {
                const int hoff = s * 32 + q * 8;
                short8 Bh = BF(&h0hi[bq][hoff]);
                short8 Bl = BF(&h0lo[bq][hoff]);
                short8 Ch = BF(&h1hi[bq][hoff]);
                short8 Cl = BF(&h1lo[bq][hoff]);
                const short* fs1 = fb1 + s * 512;
                const short* fs2 = fb2 + s * 512;
                MS3(Yi, 0) MS3(Yf, 1) MS3(Yg, 2) MS3(Yo, 3)
            }
            float part = 0.0f;
            GATE1L(0) GATE1L(1) GATE1L(2) GATE1L(3)
            part += __shfl_xor(part, 16, 64);
            part += __shfl_xor(part, 32, 64);
            if (q == 0)                  // direct device-scope posc store (no LDS restage)
                stf_dev(poscw + j * 32 + (w - 2) * 16 + bq, part);
        }
        vmcnt0();                        // every wave: ALL its stores (hx + posc) acked
        __syncthreads();
        if (tid == 0)                    // all waves' data at coherence point -> flag
            st32_dev(myflag, (u32)(p + 1));
        if (tid < 8) {                   // spin on device-scope loads
            const u32 tgt = (u32)(p + 1);
            int it = 0;
            while (ld32_poll(flg + g * 8 + tid) < tgt) {
                __builtin_amdgcn_s_sleep(1);
                if (++it > 50000) break; // finite-wrong, never hang
            }
        }
        __syncthreads();
        // ---- pipelined device-scope readback: h0(p+1), h1(p), posc(p)
        u32x4 va0, va1, va2, va3, vb0, vb1, vb2, vb3;
        float po[16];
        const u32x4* s4a = (const u32x4*)hx0w;
        const u32x4* s4b = (const u32x4*)hx1w;
        const bool doout = (p >= 1) && (j == 0) && (tid < 16);
        if (p < TT) {
            va0 = ld128_dev(s4a + tid);
            va1 = ld128_dev(s4a + tid + 256);
            va2 = ld128_dev(s4a + tid + 512);
            va3 = ld128_dev(s4a + tid + 768);
        }
        if (p >= 1) {
            vb0 = ld128_dev(s4b + tid);
            vb1 = ld128_dev(s4b + tid + 256);
            vb2 = ld128_dev(s4b + tid + 512);
            vb3 = ld128_dev(s4b + tid + 768);
        }
        if (doout) {
            const float* pp = poscw + tid;           // [jj][half][b=tid]
#pragma unroll
            for (int jj = 0; jj < 8; ++jj) {
                po[2 * jj]     = ldf_dev(pp + jj * 32);
                po[2 * jj + 1] = ldf_dev(pp + jj * 32 + 16);
            }
        }
        vmcnt0();                        // all readback loads complete
        if (p < TT) {
            KEEP(va0); KEEP(va1); KEEP(va2); KEEP(va3);
            UNPACK0(va0, tid); UNPACK0(va1, tid + 256);
            UNPACK0(va2, tid + 512); UNPACK0(va3, tid + 768);
        }
        if (p >= 1) {
            KEEP(vb0); KEEP(vb1); KEEP(vb2); KEEP(vb3);
            UNPACK1(vb0, tid); UNPACK1(vb1, tid + 256);
            UNPACK1(vb2, tid + 512); UNPACK1(vb3, tid + 768);
        }
        if (doout) {                     // assemble out[t = p-1]
#pragma unroll
            for (int jj = 0; jj < 16; ++jj) KEEP(po[jj]);
            float o = bho;
#pragma unroll
            for (int jj = 0; jj < 16; ++jj) o += po[jj];
            out[(bglo + tid) * TT + (p - 1)] = o;    // plain store: host-read after kernel end
        }
        __syncthreads();                 // LDS h planes ready for next phase
    }
}

extern "C" void kernel_launch(void* const* d_in, const int* in_sizes, int n_in,
                              void* d_out, int out_size, void* d_ws, size_t ws_size,
                              hipStream_t stream)
{
    const float* latent = (const float*)d_in[0];
    const float* W_lh   = (const float*)d_in[1];
    const float* b_lh   = (const float*)d_in[2];
    // d_in[3] = W_ih0: unused (layer-0 inputs are all-zero)
    const float* W_hh0  = (const float*)d_in[4];
    const float* b_ih0  = (const float*)d_in[5];
    const float* b_hh0  = (const float*)d_in[6];
    const float* W_ih1  = (const float*)d_in[7];
    const float* W_hh1  = (const float*)d_in[8];
    const float* b_ih1  = (const float*)d_in[9];
    const float* b_hh1  = (const float*)d_in[10];
    const float* W_ho   = (const float*)d_in[11];
    const float* b_ho   = (const float*)d_in[12];

    char* ws = (char*)d_ws;
    short* frag = (short*)ws;                     // 1,572,864 B
    u32*   hx0  = (u32*)(ws + 1572864);           //   524,288 B (2 parities)
    u32*   hx1  = (u32*)(ws + 2097152);           //   524,288 B
    float* posc = (float*)(ws + 2621440);         //    32,768 B (2 parities x 16g x 8j x 2 x 16)
    u32*   flg  = (u32*)(ws + 2654208);           //       512 B   (total ~2.65 MB)

    zero_flags<<<dim3(1), dim3(128), 0, stream>>>(flg);
    lstm_skew<<<dim3(128), dim3(256), 0, stream>>>(latent, W_lh, b_lh,
                                                   W_hh0, b_ih0, b_hh0,
                                                   W_ih1, W_hh1, b_ih1, b_hh1,
                                                   W_ho, b_ho,
                                                   frag, hx0, hx1, posc, flg,
                                                   (float*)d_out);
}